// Round 1
// baseline (180.859 us; speedup 1.0000x reference)
//
#include <hip/hip_runtime.h>

// Problem constants
#define HW   576      // 24*24 pixels
#define CC   512      // channels
#define PW   30       // padded H/W
#define PPK  1024     // padded p rows (900 real + pad)
#define NS   4        // p slices in attn
#define SP   256      // p per slice

typedef float f32x4 __attribute__((ext_vector_type(4)));
typedef short s16x8 __attribute__((ext_vector_type(8)));

__device__ __forceinline__ unsigned short f2bf(float f) {
    unsigned u = __float_as_uint(f);                      // RNE fp32->bf16
    return (unsigned short)((u + 0x7FFFu + ((u >> 16) & 1u)) >> 16);
}
__device__ __forceinline__ float bf2f(unsigned short h) {
    return __uint_as_float((unsigned)h << 16);
}
// reflect-pad row map; p>=900 -> zero row 576 of xT
__device__ __forceinline__ int smapf(int p) {
    if (p >= 900) return 576;
    const int y = p / PW, xw = p - y * PW;
    int iy = y - 3;  iy = (iy < 0) ? -iy : (iy > 23 ? 46 - iy : iy);
    int ix = xw - 3; ix = (ix < 0) ? -ix : (ix > 23 ? 46 - ix : ix);
    return iy * 24 + ix;
}

// Workspace byte offsets (total ~7.36 MB)
#define OFF_QT 0u         // bf16 [8][576][64]
#define OFF_KT 589824u    // bf16 [8][1024][64]
#define OFF_VP 1638400u   // bf16 [8][64][1024]
#define OFF_MP 2686976u   // f32  [8][4][576]
#define OFF_LP 2760704u   // f32  [8][4][576]
#define OFF_OP 2834432u   // bf16 [8][4][576][64]
#define OFF_XT 5193728u   // bf16 [577][512] (row 576 = zeros)
#define OFF_WB 5784576u   // bf16 [3][512][512]
#define OFF_CNT 7357440u  // i32  [288] slice-done counters (zeroed by cvtT)

// ---------------------------------------------------------------------------
// Kernel 0: build xT (bf16 transpose of x, LDS-tiled 64x64, + zero row) and
// wb (bf16 copy of Wq/Wk/Wv). Also zeroes the 288 combine counters (block 72).
// grid 457 blocks x 256.
// ---------------------------------------------------------------------------
__global__ __launch_bounds__(256) void cvtT(
    const float* __restrict__ x,
    const float* __restrict__ Wq, const float* __restrict__ Wk,
    const float* __restrict__ Wv,
    unsigned short* __restrict__ xT, unsigned short* __restrict__ wb,
    int* __restrict__ cnt)
{
    const int b = blockIdx.x, t = threadIdx.x;
    if (b < 72) {                                  // transpose: 9 pix-tiles x 8 chan-tiles
        __shared__ float tile[64][65];             // [chan][pix]; stride 65 -> 2-way free
        const int pt = b % 9, ct = b / 9;
        const int p0 = pt * 64, c0 = ct * 64;
        const int tr = t >> 4, tc4 = (t & 15) * 4;
        #pragma unroll
        for (int cr = 0; cr < 4; ++cr) {
            const int row = cr * 16 + tr;          // chan_local
            const float4 v = *(const float4*)&x[(size_t)(c0 + row) * HW + p0 + tc4];
            tile[row][tc4 + 0] = v.x;
            tile[row][tc4 + 1] = v.y;
            tile[row][tc4 + 2] = v.z;
            tile[row][tc4 + 3] = v.w;
        }
        __syncthreads();
        #pragma unroll
        for (int cr = 0; cr < 4; ++cr) {
            const int prow = cr * 16 + tr;         // pix_local
            ushort4 o;
            o.x = f2bf(tile[tc4 + 0][prow]);
            o.y = f2bf(tile[tc4 + 1][prow]);
            o.z = f2bf(tile[tc4 + 2][prow]);
            o.w = f2bf(tile[tc4 + 3][prow]);
            *(ushort4*)&xT[(size_t)(p0 + prow) * CC + c0 + tc4] = o;
        }
    } else if (b == 72) {                          // zero row 576 + counters
        if (t < 128) *(ushort4*)&xT[(size_t)576 * CC + t * 4] = (ushort4){0, 0, 0, 0};
        for (int i = t; i < 288; i += 256) cnt[i] = 0;
    } else {                                       // W convert: 384 blocks x 2048 elems
        const int wi = (b - 73) * 2048 + t * 8;
        const int sel = wi >> 18, off = wi & 262143;
        const float* src = (sel == 0) ? Wq : (sel == 1) ? Wk : Wv;
        const float4 v0 = *(const float4*)&src[off];
        const float4 v1 = *(const float4*)&src[off + 4];
        ushort4 o0, o1;
        o0.x = f2bf(v0.x); o0.y = f2bf(v0.y); o0.z = f2bf(v0.z); o0.w = f2bf(v0.w);
        o1.x = f2bf(v1.x); o1.y = f2bf(v1.y); o1.z = f2bf(v1.z); o1.w = f2bf(v1.w);
        *(ushort4*)&wb[wi]     = o0;
        *(ushort4*)&wb[wi + 4] = o1;
    }
}

// ---------------------------------------------------------------------------
// Kernel 1: Q/K/V projections, barrier-free MFMA. One wave = one 16x32 output
// tile, K=512 in-register; BOTH operands are contiguous 16B row-fragments
// loaded straight from global (xT rows / W rows; reflect-pad via smapf row
// indirection). 2624 waves = 656 blocks x 256 (4 indep waves). No LDS.
//   sel 0 (576 waves):  D[pix][chan]  -> qT [head][pix][64]
//   sel 1 (1024 waves): D[p][chan]    -> kT [head][p][64]   (pad rows: bias, harmless)
//   sel 2 (1024 waves): D[chan][p]    -> vP [head][64][p]   (pad cols: bias, harmless)
// ---------------------------------------------------------------------------
__global__ __launch_bounds__(256) void qkv_direct(
    const unsigned short* __restrict__ xT, const unsigned short* __restrict__ wb,
    const float* __restrict__ bq, const float* __restrict__ bk,
    const float* __restrict__ bv,
    unsigned short* __restrict__ qT, unsigned short* __restrict__ kT,
    unsigned short* __restrict__ vP)
{
    const int t = threadIdx.x;
    const int w = blockIdx.x * 4 + (t >> 6);
    const int lane = t & 63, fr = lane & 15, u = lane >> 4;

    int sel, m0, n0;
    if (w < 576)       { sel = 0; m0 = (w >> 4) << 4;               n0 = (w & 15) << 5; }
    else if (w < 1600) { const int k = w - 576;  sel = 1; m0 = (k >> 4) << 4; n0 = (k & 15) << 5; }
    else               { const int k = w - 1600; sel = 2; m0 = (k >> 5) << 4; n0 = (k & 31) << 5; }

    const unsigned short *A, *B;
    int ar, bn0, bn1;
    if (sel == 0)      { A = xT;          B = wb;          ar = m0 + fr;
                         bn0 = n0 + fr;          bn1 = n0 + 16 + fr; }
    else if (sel == 1) { A = xT;          B = wb + 262144; ar = smapf(m0 + fr);
                         bn0 = n0 + fr;          bn1 = n0 + 16 + fr; }
    else               { A = wb + 524288; B = xT;          ar = m0 + fr;
                         bn0 = smapf(n0 + fr);   bn1 = smapf(n0 + 16 + fr); }

    const unsigned short* Ap  = A + (size_t)ar  * CC + u * 8;
    const unsigned short* Bp0 = B + (size_t)bn0 * CC + u * 8;
    const unsigned short* Bp1 = B + (size_t)bn1 * CC + u * 8;

    f32x4 acc0 = (f32x4){0.f, 0.f, 0.f, 0.f};
    f32x4 acc1 = (f32x4){0.f, 0.f, 0.f, 0.f};
    #pragma unroll 8
    for (int k0 = 0; k0 < CC; k0 += 32) {
        const s16x8 a  = *(const s16x8*)(Ap  + k0);
        const s16x8 b0 = *(const s16x8*)(Bp0 + k0);
        const s16x8 b1 = *(const s16x8*)(Bp1 + k0);
        acc0 = __builtin_amdgcn_mfma_f32_16x16x32_bf16(a, b0, acc0, 0, 0, 0);
        acc1 = __builtin_amdgcn_mfma_f32_16x16x32_bf16(a, b1, acc1, 0, 0, 0);
    }

    // epilogue: C/D layout col(fr)=n, row(u*4+r)=m
    #pragma unroll
    for (int ni = 0; ni < 2; ++ni) {
        const f32x4 acc = ni ? acc1 : acc0;
        #pragma unroll
        for (int r = 0; r < 4; ++r) {
            const int m = m0 + u * 4 + r;
            const int n = n0 + ni * 16 + fr;
            if (sel == 0) {
                qT[((size_t)(n >> 6) * HW + m) * 64 + (n & 63)] = f2bf(acc[r] + bq[n]);
            } else if (sel == 1) {
                kT[((size_t)(n >> 6) * PPK + m) * 64 + (n & 63)] = f2bf(acc[r] + bk[n]);
            } else {
                vP[((size_t)(m >> 6) * 64 + (m & 63)) * PPK + n] = f2bf(acc[r] + bv[m]);
            }
        }
    }
}

// ---------------------------------------------------------------------------
// Kernel 2: MFMA attention, split-p partials + FUSED combine. Block =
// (16q, slice, head); grid (36, 4, 8) = 1152 blocks, 4 waves. Per-slice
// (m, l, O) partials to workspace; the LAST block per (q-tile, head) to
// finish (device-scope atomic counter) merges the 4 slices and writes
// out = gamma*O/l + x directly. Removes the separate combine kernel.
// ---------------------------------------------------------------------------
__global__ __launch_bounds__(256) void attn3(
    const unsigned short* __restrict__ qT, const unsigned short* __restrict__ kT,
    const unsigned short* __restrict__ vP, float* __restrict__ mP,
    float* __restrict__ lP, unsigned short* __restrict__ Op,
    const float* __restrict__ x, const float* __restrict__ gamma,
    float* __restrict__ out, int* __restrict__ cnt)
{
    const int q0 = blockIdx.x * 16;
    const int s  = blockIdx.y;
    const int hd = blockIdx.z;
    const int t  = threadIdx.x;
    const int lane = t & 63, w = t >> 6;
    const int fr = lane & 15, u = lane >> 4;

    __shared__ float cnt_s[SP];                   // multiplicity table
    __shared__ __align__(16) unsigned short Wl[16 * 272];  // weights [q][p+pad]
    __shared__ float mw[64], lw[64];
    __shared__ int lastf;

    if (t < SP) {                                 // cnt(y)*cnt(x), 0 for pads
        const int p = s * SP + t;
        float c = 0.f;
        if (p < 900) {
            const int y = p / PW, xw = p - y * PW;
            int cy = y + 1;  if (PW - y  < cy) cy = PW - y;  if (cy > 7) cy = 7;
            int cx = xw + 1; if (PW - xw < cx) cx = PW - xw; if (cx > 7) cx = 7;
            c = (float)(cy * cx);
        }
        cnt_s[t] = c;
    }

    // q B-frags (shared across this wave's p-tiles)
    const unsigned short* qrow = qT + ((size_t)hd * HW + q0 + fr) * 64 + u * 8;
    const s16x8 b0 = *(const s16x8*)qrow;
    const s16x8 b1 = *(const s16x8*)(qrow + 32);

    // QK: 4 E^T tiles (16p x 16q) per wave
    f32x4 e[4];
    #pragma unroll
    for (int t4 = 0; t4 < 4; ++t4) {
        const unsigned short* krow =
            kT + ((size_t)hd * PPK + s * SP + w * 64 + t4 * 16 + fr) * 64 + u * 8;
        const s16x8 a0 = *(const s16x8*)krow;
        const s16x8 a1 = *(const s16x8*)(krow + 32);
        f32x4 a = (f32x4){0.f, 0.f, 0.f, 0.f};
        a = __builtin_amdgcn_mfma_f32_16x16x32_bf16(a0, b0, a, 0, 0, 0);
        a = __builtin_amdgcn_mfma_f32_16x16x32_bf16(a1, b1, a, 0, 0, 0);
        e[t4] = a;
    }

    // per-q max (all regs share q = fr; cross-quad via 2 shuffles)
    float m = -1e30f;
    #pragma unroll
    for (int t4 = 0; t4 < 4; ++t4)
        #pragma unroll
        for (int r = 0; r < 4; ++r) m = fmaxf(m, e[t4][r]);
    m = fmaxf(m, __shfl_xor(m, 16));
    m = fmaxf(m, __shfl_xor(m, 32));
    if (lane < 16) mw[w * 16 + lane] = m;
    __syncthreads();
    const float mq = fmaxf(fmaxf(mw[fr], mw[16 + fr]), fmaxf(mw[32 + fr], mw[48 + fr]));

    // weights = cnt * exp(e - mq): bf16 into Wl; per-q partial sums
    float sum = 0.f;
    #pragma unroll
    for (int t4 = 0; t4 < 4; ++t4) {
        unsigned short wb4[4];
        #pragma unroll
        for (int r = 0; r < 4; ++r) {
            const float wv2 = cnt_s[w * 64 + t4 * 16 + u * 4 + r] *
                              __expf(e[t4][r] - mq);
            sum += wv2;
            wb4[r] = f2bf(wv2);
        }
        const int ho = fr * 272 + w * 64 + t4 * 16 + u * 4;
        *(unsigned*)&Wl[ho]     = (unsigned)wb4[0] | ((unsigned)wb4[1] << 16);
        *(unsigned*)&Wl[ho + 2] = (unsigned)wb4[2] | ((unsigned)wb4[3] << 16);
    }
    sum += __shfl_xor(sum, 16);
    sum += __shfl_xor(sum, 32);
    if (lane < 16) lw[w * 16 + lane] = sum;
    __syncthreads();

    if (t < 16) {                                 // store per-slice stats
        const float lq = lw[t] + lw[16 + t] + lw[32 + t] + lw[48 + t];
        const float mq2 = fmaxf(fmaxf(mw[t], mw[16 + t]),
                                fmaxf(mw[32 + t], mw[48 + t]));
        const int si = (hd * NS + s) * HW + q0 + t;
        lP[si] = lq;
        mP[si] = mq2;
    }

    // PV: wave w owns d-tile w; O[16q][16d] over this slice's 256 p
    f32x4 o = (f32x4){0.f, 0.f, 0.f, 0.f};
    const unsigned short* vrow =
        vP + ((size_t)hd * 64 + w * 16 + fr) * PPK + s * SP + u * 8;
    #pragma unroll
    for (int c = 0; c < 8; ++c) {
        const s16x8 aw = *(const s16x8*)&Wl[fr * 272 + c * 32 + u * 8];
        const s16x8 bv2 = *(const s16x8*)(vrow + c * 32);
        o = __builtin_amdgcn_mfma_f32_16x16x32_bf16(aw, bv2, o, 0, 0, 0);
    }
    #pragma unroll
    for (int r = 0; r < 4; ++r) {                 // C layout: row=q, col=d
        const size_t oi =
            ((size_t)(hd * NS + s) * HW + q0 + u * 4 + r) * 64 + w * 16 + fr;
        Op[oi] = f2bf(o[r]);
    }

    // ----- fused combine: last-finishing block per (q-tile, head) merges -----
    __syncthreads();                              // all stores drained (vmcnt 0)
    if (t == 0) {
        __threadfence();                          // release: L2 writeback
        lastf = (atomicAdd(&cnt[hd * 36 + blockIdx.x], 1) == NS - 1);
    }
    __syncthreads();
    if (!lastf) return;
    __threadfence();                              // acquire: invalidate stale lines

    // layout A (coalesced Op reads): qA = t>>4, dA = (t&15)*4
    const int qA = t >> 4, dA = (t & 15) << 2;
    const int q  = q0 + qA;
    const int sb = (hd * NS) * HW + q;
    const float m0_ = mP[sb], m1_ = mP[sb + HW];
    const float m2_ = mP[sb + 2 * HW], m3_ = mP[sb + 3 * HW];
    const float ms = fmaxf(fmaxf(m0_, m1_), fmaxf(m2_, m3_));
    const float aa[NS] = {__expf(m0_ - ms), __expf(m1_ - ms),
                          __expf(m2_ - ms), __expf(m3_ - ms)};
    const float l = lP[sb] * aa[0] + lP[sb + HW] * aa[1] +
                    lP[sb + 2 * HW] * aa[2] + lP[sb + 3 * HW] * aa[3];

    float o4[4] = {0.f, 0.f, 0.f, 0.f};
    #pragma unroll
    for (int s2 = 0; s2 < NS; ++s2) {
        const ushort4 uv = *(const ushort4*)&Op[((size_t)(hd * NS + s2) * HW + q) * 64 + dA];
        o4[0] = fmaf(aa[s2], bf2f(uv.x), o4[0]);
        o4[1] = fmaf(aa[s2], bf2f(uv.y), o4[1]);
        o4[2] = fmaf(aa[s2], bf2f(uv.z), o4[2]);
        o4[3] = fmaf(aa[s2], bf2f(uv.w), o4[3]);
    }

    // LDS transpose (reuse Wl: 64*17*4 = 4352 B <= 8704 B) + per-q scale in mw
    float* Ol = (float*)Wl;
    #pragma unroll
    for (int j = 0; j < 4; ++j) Ol[(dA + j) * 17 + qA] = o4[j];
    if ((t & 15) == 0) mw[qA] = gamma[0] / l;
    __syncthreads();

    // layout B (coalesced out/x): qB = t&15, d = (t>>4)*4 + i
    const int qB = t & 15, d0 = (t >> 4) << 2;
    const float sc = mw[qB];
    #pragma unroll
    for (int i = 0; i < 4; ++i) {
        const int d = d0 + i;
        const size_t gi = (size_t)(hd * 64 + d) * HW + q0 + qB;
        out[gi] = fmaf(sc, Ol[d * 17 + qB], x[gi]);
    }
}

// ---------------------------------------------------------------------------
extern "C" void kernel_launch(void* const* d_in, const int* in_sizes, int n_in,
                              void* d_out, int out_size, void* d_ws, size_t ws_size,
                              hipStream_t stream) {
    const float* x     = (const float*)d_in[0];
    const float* Wq    = (const float*)d_in[1];
    const float* bq    = (const float*)d_in[2];
    const float* Wk    = (const float*)d_in[3];
    const float* bk    = (const float*)d_in[4];
    const float* Wv    = (const float*)d_in[5];
    const float* bv    = (const float*)d_in[6];
    const float* gamma = (const float*)d_in[7];
    float* out = (float*)d_out;

    char* wsb = (char*)d_ws;
    unsigned short* qT = (unsigned short*)(wsb + OFF_QT);
    unsigned short* kT = (unsigned short*)(wsb + OFF_KT);
    unsigned short* vP = (unsigned short*)(wsb + OFF_VP);
    float*          mP = (float*)(wsb + OFF_MP);
    float*          lP = (float*)(wsb + OFF_LP);
    unsigned short* Op = (unsigned short*)(wsb + OFF_OP);
    unsigned short* xT = (unsigned short*)(wsb + OFF_XT);
    unsigned short* wb = (unsigned short*)(wsb + OFF_WB);
    int*           cnt = (int*)(wsb + OFF_CNT);

    cvtT<<<dim3(457), 256, 0, stream>>>(x, Wq, Wk, Wv, xT, wb, cnt);
    qkv_direct<<<dim3(656), 256, 0, stream>>>(xT, wb, bq, bk, bv, qT, kT, vP);
    attn3<<<dim3(36, NS, 8), 256, 0, stream>>>(qT, kT, vP, mP, lP, Op,
                                               x, gamma, out, cnt);
}

// Round 2
// 108.999 us; speedup vs baseline: 1.6593x; 1.6593x over previous
//
#include <hip/hip_runtime.h>

// Problem constants
#define HW   576      // 24*24 pixels
#define CC   512      // channels
#define PW   30       // padded H/W
#define PPK  1024     // padded p rows (900 real + pad)

typedef float f32x4 __attribute__((ext_vector_type(4)));
typedef short s16x8 __attribute__((ext_vector_type(8)));

__device__ __forceinline__ unsigned short f2bf(float f) {
    unsigned u = __float_as_uint(f);                      // RNE fp32->bf16
    return (unsigned short)((u + 0x7FFFu + ((u >> 16) & 1u)) >> 16);
}
__device__ __forceinline__ float bf2f(unsigned short h) {
    return __uint_as_float((unsigned)h << 16);
}
// reflect-pad row map; p>=900 -> zero row 576 of xT
__device__ __forceinline__ int smapf(int p) {
    if (p >= 900) return 576;
    const int y = p / PW, xw = p - y * PW;
    int iy = y - 3;  iy = (iy < 0) ? -iy : (iy > 23 ? 46 - iy : iy);
    int ix = xw - 3; ix = (ix < 0) ? -ix : (ix > 23 ? 46 - ix : ix);
    return iy * 24 + ix;
}

// Workspace byte offsets (total ~4.85 MB)
#define OFF_QT 0u         // bf16 [8][576][64]
#define OFF_KT 589824u    // bf16 [8][1024][64]
#define OFF_VP 1638400u   // bf16 [8][64][1024]
#define OFF_XT 2686976u   // bf16 [577][512] (row 576 = zeros)
#define OFF_WB 3277824u   // bf16 [3][512][512]

// ---------------------------------------------------------------------------
// Kernel 0: build xT (bf16 transpose of x, LDS-tiled 64x64, + zero row) and
// wb (bf16 copy of Wq/Wk/Wv). grid 457 blocks x 256.
// ---------------------------------------------------------------------------
__global__ __launch_bounds__(256) void cvtT(
    const float* __restrict__ x,
    const float* __restrict__ Wq, const float* __restrict__ Wk,
    const float* __restrict__ Wv,
    unsigned short* __restrict__ xT, unsigned short* __restrict__ wb)
{
    const int b = blockIdx.x, t = threadIdx.x;
    if (b < 72) {                                  // transpose: 9 pix-tiles x 8 chan-tiles
        __shared__ float tile[64][65];             // [chan][pix]; stride 65 -> 2-way free
        const int pt = b % 9, ct = b / 9;
        const int p0 = pt * 64, c0 = ct * 64;
        const int tr = t >> 4, tc4 = (t & 15) * 4;
        #pragma unroll
        for (int cr = 0; cr < 4; ++cr) {
            const int row = cr * 16 + tr;          // chan_local
            const float4 v = *(const float4*)&x[(size_t)(c0 + row) * HW + p0 + tc4];
            tile[row][tc4 + 0] = v.x;
            tile[row][tc4 + 1] = v.y;
            tile[row][tc4 + 2] = v.z;
            tile[row][tc4 + 3] = v.w;
        }
        __syncthreads();
        #pragma unroll
        for (int cr = 0; cr < 4; ++cr) {
            const int prow = cr * 16 + tr;         // pix_local
            ushort4 o;
            o.x = f2bf(tile[tc4 + 0][prow]);
            o.y = f2bf(tile[tc4 + 1][prow]);
            o.z = f2bf(tile[tc4 + 2][prow]);
            o.w = f2bf(tile[tc4 + 3][prow]);
            *(ushort4*)&xT[(size_t)(p0 + prow) * CC + c0 + tc4] = o;
        }
    } else if (b == 72) {                          // zero row 576
        if (t < 128) *(ushort4*)&xT[(size_t)576 * CC + t * 4] = (ushort4){0, 0, 0, 0};
    } else {                                       // W convert: 384 blocks x 2048 elems
        const int wi = (b - 73) * 2048 + t * 8;
        const int sel = wi >> 18, off = wi & 262143;
        const float* src = (sel == 0) ? Wq : (sel == 1) ? Wk : Wv;
        const float4 v0 = *(const float4*)&src[off];
        const float4 v1 = *(const float4*)&src[off + 4];
        ushort4 o0, o1;
        o0.x = f2bf(v0.x); o0.y = f2bf(v0.y); o0.z = f2bf(v0.z); o0.w = f2bf(v0.w);
        o1.x = f2bf(v1.x); o1.y = f2bf(v1.y); o1.z = f2bf(v1.z); o1.w = f2bf(v1.w);
        *(ushort4*)&wb[wi]     = o0;
        *(ushort4*)&wb[wi + 4] = o1;
    }
}

// ---------------------------------------------------------------------------
// Kernel 1: Q/K/V projections, barrier-free MFMA. One wave = one 16x32 output
// tile, K=512 in-register; BOTH operands are contiguous 16B row-fragments
// loaded straight from global (xT rows / W rows; reflect-pad via smapf row
// indirection). 2624 waves = 656 blocks x 256 (4 indep waves). No LDS.
//   sel 0 (576 waves):  D[pix][chan]  -> qT [head][pix][64]
//   sel 1 (1024 waves): D[p][chan]    -> kT [head][p][64]   (pad rows: bias, harmless)
//   sel 2 (1024 waves): D[chan][p]    -> vP [head][64][p]   (pad cols: bias, harmless)
// ---------------------------------------------------------------------------
__global__ __launch_bounds__(256) void qkv_direct(
    const unsigned short* __restrict__ xT, const unsigned short* __restrict__ wb,
    const float* __restrict__ bq, const float* __restrict__ bk,
    const float* __restrict__ bv,
    unsigned short* __restrict__ qT, unsigned short* __restrict__ kT,
    unsigned short* __restrict__ vP)
{
    const int t = threadIdx.x;
    const int w = blockIdx.x * 4 + (t >> 6);
    const int lane = t & 63, fr = lane & 15, u = lane >> 4;

    int sel, m0, n0;
    if (w < 576)       { sel = 0; m0 = (w >> 4) << 4;               n0 = (w & 15) << 5; }
    else if (w < 1600) { const int k = w - 576;  sel = 1; m0 = (k >> 4) << 4; n0 = (k & 15) << 5; }
    else               { const int k = w - 1600; sel = 2; m0 = (k >> 5) << 4; n0 = (k & 31) << 5; }

    const unsigned short *A, *B;
    int ar, bn0, bn1;
    if (sel == 0)      { A = xT;          B = wb;          ar = m0 + fr;
                         bn0 = n0 + fr;          bn1 = n0 + 16 + fr; }
    else if (sel == 1) { A = xT;          B = wb + 262144; ar = smapf(m0 + fr);
                         bn0 = n0 + fr;          bn1 = n0 + 16 + fr; }
    else               { A = wb + 524288; B = xT;          ar = m0 + fr;
                         bn0 = smapf(n0 + fr);   bn1 = smapf(n0 + 16 + fr); }

    const unsigned short* Ap  = A + (size_t)ar  * CC + u * 8;
    const unsigned short* Bp0 = B + (size_t)bn0 * CC + u * 8;
    const unsigned short* Bp1 = B + (size_t)bn1 * CC + u * 8;

    f32x4 acc0 = (f32x4){0.f, 0.f, 0.f, 0.f};
    f32x4 acc1 = (f32x4){0.f, 0.f, 0.f, 0.f};
    #pragma unroll 8
    for (int k0 = 0; k0 < CC; k0 += 32) {
        const s16x8 a  = *(const s16x8*)(Ap  + k0);
        const s16x8 b0 = *(const s16x8*)(Bp0 + k0);
        const s16x8 b1 = *(const s16x8*)(Bp1 + k0);
        acc0 = __builtin_amdgcn_mfma_f32_16x16x32_bf16(a, b0, acc0, 0, 0, 0);
        acc1 = __builtin_amdgcn_mfma_f32_16x16x32_bf16(a, b1, acc1, 0, 0, 0);
    }

    // epilogue: C/D layout col(fr)=n, row(u*4+r)=m
    #pragma unroll
    for (int ni = 0; ni < 2; ++ni) {
        const f32x4 acc = ni ? acc1 : acc0;
        #pragma unroll
        for (int r = 0; r < 4; ++r) {
            const int m = m0 + u * 4 + r;
            const int n = n0 + ni * 16 + fr;
            if (sel == 0) {
                qT[((size_t)(n >> 6) * HW + m) * 64 + (n & 63)] = f2bf(acc[r] + bq[n]);
            } else if (sel == 1) {
                kT[((size_t)(n >> 6) * PPK + m) * 64 + (n & 63)] = f2bf(acc[r] + bk[n]);
            } else {
                vP[((size_t)(m >> 6) * 64 + (m & 63)) * PPK + n] = f2bf(acc[r] + bv[m]);
            }
        }
    }
}

// ---------------------------------------------------------------------------
// Kernel 2: single-pass MFMA attention + epilogue. Block = (16q, head);
// grid (36, 8) = 288 blocks, 4 waves. Wave w owns p-slice [w*256, w*256+256)
// for QK and weight generation; all 1024 p of bf16 weights live in LDS.
// Softmax max/sum reduce across waves via LDS + __syncthreads only — NO
// cross-block traffic, NO fences (R1 post-mortem: device fences on multi-XCD
// L2 cost ~100 us). PV: wave w owns d-tile w over all 1024 p. Block writes
// out = gamma*O/l + x directly.
// ---------------------------------------------------------------------------
#define WLS 1040      // Wl row stride (shorts); bank step 8 -> matches verified attn3 pattern
__global__ __launch_bounds__(256) void attn4(
    const unsigned short* __restrict__ qT, const unsigned short* __restrict__ kT,
    const unsigned short* __restrict__ vP, const float* __restrict__ x,
    const float* __restrict__ gamma, float* __restrict__ out)
{
    const int q0 = blockIdx.x * 16;
    const int hd = blockIdx.y;
    const int t  = threadIdx.x;
    const int lane = t & 63, w = t >> 6;
    const int fr = lane & 15, u = lane >> 4;

    __shared__ float cnt_s[PPK];                  // multiplicity table (0 for pads)
    __shared__ __align__(16) unsigned short Wl[16 * WLS];  // weights [q][1024p]
    __shared__ float mw[64], lw[64], sca[16];

    for (int i = t; i < PPK; i += 256) {          // cnt(y)*cnt(x), 0 for pads
        float c = 0.f;
        if (i < 900) {
            const int y = i / PW, xw = i - y * PW;
            int cy = y + 1;  if (PW - y  < cy) cy = PW - y;  if (cy > 7) cy = 7;
            int cx = xw + 1; if (PW - xw < cx) cx = PW - xw; if (cx > 7) cx = 7;
            c = (float)(cy * cx);
        }
        cnt_s[i] = c;
    }

    // q B-frags (shared across this wave's p-tiles)
    const unsigned short* qrow = qT + ((size_t)hd * HW + q0 + fr) * 64 + u * 8;
    const s16x8 b0 = *(const s16x8*)qrow;
    const s16x8 b1 = *(const s16x8*)(qrow + 32);

    // QK: 16 E^T tiles (16p x 16q) per wave -> this wave's 256 p
    f32x4 e[16];
    #pragma unroll
    for (int t4 = 0; t4 < 16; ++t4) {
        const unsigned short* krow =
            kT + ((size_t)hd * PPK + w * 256 + t4 * 16 + fr) * 64 + u * 8;
        const s16x8 a0 = *(const s16x8*)krow;
        const s16x8 a1 = *(const s16x8*)(krow + 32);
        f32x4 a = (f32x4){0.f, 0.f, 0.f, 0.f};
        a = __builtin_amdgcn_mfma_f32_16x16x32_bf16(a0, b0, a, 0, 0, 0);
        a = __builtin_amdgcn_mfma_f32_16x16x32_bf16(a1, b1, a, 0, 0, 0);
        e[t4] = a;
    }

    // per-q max over this wave's 256 p (regs share q = fr; cross-quad via shuffles)
    float m = -1e30f;
    #pragma unroll
    for (int t4 = 0; t4 < 16; ++t4)
        #pragma unroll
        for (int r = 0; r < 4; ++r) m = fmaxf(m, e[t4][r]);
    m = fmaxf(m, __shfl_xor(m, 16));
    m = fmaxf(m, __shfl_xor(m, 32));
    if (lane < 16) mw[w * 16 + lane] = m;
    __syncthreads();
    const float mq = fmaxf(fmaxf(mw[fr], mw[16 + fr]), fmaxf(mw[32 + fr], mw[48 + fr]));

    // weights = cnt * exp(e - mq): bf16 into Wl; per-q partial sums
    float sum = 0.f;
    #pragma unroll
    for (int t4 = 0; t4 < 16; ++t4) {
        const float4 c4 = *(const float4*)&cnt_s[w * 256 + t4 * 16 + u * 4];
        const float cw[4] = {c4.x, c4.y, c4.z, c4.w};
        unsigned short wb4[4];
        #pragma unroll
        for (int r = 0; r < 4; ++r) {
            const float wv2 = cw[r] * __expf(e[t4][r] - mq);
            sum += wv2;
            wb4[r] = f2bf(wv2);
        }
        const int ho = fr * WLS + w * 256 + t4 * 16 + u * 4;
        *(unsigned*)&Wl[ho]     = (unsigned)wb4[0] | ((unsigned)wb4[1] << 16);
        *(unsigned*)&Wl[ho + 2] = (unsigned)wb4[2] | ((unsigned)wb4[3] << 16);
    }
    sum += __shfl_xor(sum, 16);
    sum += __shfl_xor(sum, 32);
    if (lane < 16) lw[w * 16 + lane] = sum;
    __syncthreads();                              // Wl + lw complete

    if (t < 16) {                                 // per-q scale = gamma / l
        const float lq = lw[t] + lw[16 + t] + lw[32 + t] + lw[48 + t];
        sca[t] = gamma[0] / lq;
    }

    // PV: wave w owns d-tile w; O[16q][16d] over all 1024 p
    f32x4 o = (f32x4){0.f, 0.f, 0.f, 0.f};
    const unsigned short* vrow =
        vP + ((size_t)hd * 64 + w * 16 + fr) * PPK + u * 8;
    #pragma unroll 8
    for (int c = 0; c < 32; ++c) {
        const s16x8 aw = *(const s16x8*)&Wl[fr * WLS + c * 32 + u * 8];
        const s16x8 bv2 = *(const s16x8*)(vrow + c * 32);
        o = __builtin_amdgcn_mfma_f32_16x16x32_bf16(aw, bv2, o, 0, 0, 0);
    }
    __syncthreads();                              // sca ready (and Wl dead)

    // epilogue: C layout row=q (u*4+r), col=d (w*16+fr); each lane stores a
    // float4 run of 4 consecutive q at row d -> 16B coalesced segments.
    const int d = hd * 64 + w * 16 + fr;
    const size_t gb = (size_t)d * HW + q0 + u * 4;
    const float4 x4 = *(const float4*)&x[gb];
    float4 o4;
    o4.x = fmaf(sca[u * 4 + 0], o[0], x4.x);
    o4.y = fmaf(sca[u * 4 + 1], o[1], x4.y);
    o4.z = fmaf(sca[u * 4 + 2], o[2], x4.z);
    o4.w = fmaf(sca[u * 4 + 3], o[3], x4.w);
    *(float4*)&out[gb] = o4;
}

// ---------------------------------------------------------------------------
extern "C" void kernel_launch(void* const* d_in, const int* in_sizes, int n_in,
                              void* d_out, int out_size, void* d_ws, size_t ws_size,
                              hipStream_t stream) {
    const float* x     = (const float*)d_in[0];
    const float* Wq    = (const float*)d_in[1];
    const float* bq    = (const float*)d_in[2];
    const float* Wk    = (const float*)d_in[3];
    const float* bk    = (const float*)d_in[4];
    const float* Wv    = (const float*)d_in[5];
    const float* bv    = (const float*)d_in[6];
    const float* gamma = (const float*)d_in[7];
    float* out = (float*)d_out;

    char* wsb = (char*)d_ws;
    unsigned short* qT = (unsigned short*)(wsb + OFF_QT);
    unsigned short* kT = (unsigned short*)(wsb + OFF_KT);
    unsigned short* vP = (unsigned short*)(wsb + OFF_VP);
    unsigned short* xT = (unsigned short*)(wsb + OFF_XT);
    unsigned short* wb = (unsigned short*)(wsb + OFF_WB);

    cvtT<<<dim3(457), 256, 0, stream>>>(x, Wq, Wk, Wv, xT, wb);
    qkv_direct<<<dim3(656), 256, 0, stream>>>(xT, wb, bq, bk, bv, qT, kT, vP);
    attn4<<<dim3(36, 8), 256, 0, stream>>>(qT, kT, vP, x, gamma, out);
}

// Round 3
// 107.744 us; speedup vs baseline: 1.6786x; 1.0117x over previous
//
#include <hip/hip_runtime.h>

// Problem constants
#define HW   576      // 24*24 pixels
#define CC   512      // channels
#define PW   30       // padded H/W
#define PPK  1024     // padded p rows (900 real + pad)

typedef float f32x4 __attribute__((ext_vector_type(4)));
typedef short s16x8 __attribute__((ext_vector_type(8)));

__device__ __forceinline__ unsigned short f2bf(float f) {
    unsigned u = __float_as_uint(f);                      // RNE fp32->bf16
    return (unsigned short)((u + 0x7FFFu + ((u >> 16) & 1u)) >> 16);
}
__device__ __forceinline__ float bf2f(unsigned short h) {
    return __uint_as_float((unsigned)h << 16);
}
// reflect-pad row map; p>=900 -> zero row 576 of xT
__device__ __forceinline__ int smapf(int p) {
    if (p >= 900) return 576;
    const int y = p / PW, xw = p - y * PW;
    int iy = y - 3;  iy = (iy < 0) ? -iy : (iy > 23 ? 46 - iy : iy);
    int ix = xw - 3; ix = (ix < 0) ? -ix : (ix > 23 ? 46 - ix : ix);
    return iy * 24 + ix;
}

// Workspace byte offsets (total ~4.85 MB)
#define OFF_QT 0u         // bf16 [8][576][64]
#define OFF_KT 589824u    // bf16 [8][1024][64]
#define OFF_VP 1638400u   // bf16 [8][64][1024]
#define OFF_XT 2686976u   // bf16 [577][512] (row 576 = zeros)
#define OFF_WB 3277824u   // bf16 [3][512][512]

// ---------------------------------------------------------------------------
// Kernel 0: build xT (bf16 transpose of x, LDS-tiled 64x64, + zero row) and
// wb (bf16 copy of Wq/Wk/Wv). grid 457 blocks x 256.
// ---------------------------------------------------------------------------
__global__ __launch_bounds__(256) void cvtT(
    const float* __restrict__ x,
    const float* __restrict__ Wq, const float* __restrict__ Wk,
    const float* __restrict__ Wv,
    unsigned short* __restrict__ xT, unsigned short* __restrict__ wb)
{
    const int b = blockIdx.x, t = threadIdx.x;
    if (b < 72) {                                  // transpose: 9 pix-tiles x 8 chan-tiles
        __shared__ float tile[64][65];             // [chan][pix]; stride 65 -> 2-way free
        const int pt = b % 9, ct = b / 9;
        const int p0 = pt * 64, c0 = ct * 64;
        const int tr = t >> 4, tc4 = (t & 15) * 4;
        #pragma unroll
        for (int cr = 0; cr < 4; ++cr) {
            const int row = cr * 16 + tr;          // chan_local
            const float4 v = *(const float4*)&x[(size_t)(c0 + row) * HW + p0 + tc4];
            tile[row][tc4 + 0] = v.x;
            tile[row][tc4 + 1] = v.y;
            tile[row][tc4 + 2] = v.z;
            tile[row][tc4 + 3] = v.w;
        }
        __syncthreads();
        #pragma unroll
        for (int cr = 0; cr < 4; ++cr) {
            const int prow = cr * 16 + tr;         // pix_local
            ushort4 o;
            o.x = f2bf(tile[tc4 + 0][prow]);
            o.y = f2bf(tile[tc4 + 1][prow]);
            o.z = f2bf(tile[tc4 + 2][prow]);
            o.w = f2bf(tile[tc4 + 3][prow]);
            *(ushort4*)&xT[(size_t)(p0 + prow) * CC + c0 + tc4] = o;
        }
    } else if (b == 72) {                          // zero row 576
        if (t < 128) *(ushort4*)&xT[(size_t)576 * CC + t * 4] = (ushort4){0, 0, 0, 0};
    } else {                                       // W convert: 384 blocks x 2048 elems
        const int wi = (b - 73) * 2048 + t * 8;
        const int sel = wi >> 18, off = wi & 262143;
        const float* src = (sel == 0) ? Wq : (sel == 1) ? Wk : Wv;
        const float4 v0 = *(const float4*)&src[off];
        const float4 v1 = *(const float4*)&src[off + 4];
        ushort4 o0, o1;
        o0.x = f2bf(v0.x); o0.y = f2bf(v0.y); o0.z = f2bf(v0.z); o0.w = f2bf(v0.w);
        o1.x = f2bf(v1.x); o1.y = f2bf(v1.y); o1.z = f2bf(v1.z); o1.w = f2bf(v1.w);
        *(ushort4*)&wb[wi]     = o0;
        *(ushort4*)&wb[wi + 4] = o1;
    }
}

// ---------------------------------------------------------------------------
// Kernel 1: Q/K/V projections, barrier-free MFMA, 32x32 tiles. One wave = one
// 32x32 output tile (2 A-frags x 2 B-frags x 4 accs), K=512 in-register; both
// operands contiguous 16B row-fragments from global (reflect-pad via smapf).
// 1312 waves = 328 blocks x 256 (4 indep waves). No LDS.
//   sel 0 (288 waves): D[pix][chan]  -> qT [head][pix][64]
//   sel 1 (512 waves): D[p][chan]    -> kT [head][p][64]   (pad rows: bias, harmless)
//   sel 2 (512 waves): D[chan][p]    -> vP [head][64][p]   (pad cols: bias, harmless)
// ---------------------------------------------------------------------------
__global__ __launch_bounds__(256) void qkv_direct(
    const unsigned short* __restrict__ xT, const unsigned short* __restrict__ wb,
    const float* __restrict__ bq, const float* __restrict__ bk,
    const float* __restrict__ bv,
    unsigned short* __restrict__ qT, unsigned short* __restrict__ kT,
    unsigned short* __restrict__ vP)
{
    const int t = threadIdx.x;
    const int w = blockIdx.x * 4 + (t >> 6);
    const int lane = t & 63, fr = lane & 15, u = lane >> 4;

    int sel, m0, n0;
    if (w < 288)      { sel = 0; m0 = (w >> 4) << 5;               n0 = (w & 15) << 5; }
    else if (w < 800) { const int k = w - 288; sel = 1; m0 = (k >> 4) << 5; n0 = (k & 15) << 5; }
    else              { const int k = w - 800; sel = 2; m0 = (k >> 5) << 5; n0 = (k & 31) << 5; }

    const unsigned short *A, *B;
    int ar0, ar1, bn0, bn1;
    if (sel == 0)      { A = xT;          B = wb;
                         ar0 = m0 + fr;         ar1 = m0 + 16 + fr;
                         bn0 = n0 + fr;         bn1 = n0 + 16 + fr; }
    else if (sel == 1) { A = xT;          B = wb + 262144;
                         ar0 = smapf(m0 + fr);  ar1 = smapf(m0 + 16 + fr);
                         bn0 = n0 + fr;         bn1 = n0 + 16 + fr; }
    else               { A = wb + 524288; B = xT;
                         ar0 = m0 + fr;         ar1 = m0 + 16 + fr;
                         bn0 = smapf(n0 + fr);  bn1 = smapf(n0 + 16 + fr); }

    const unsigned short* Ap0 = A + (size_t)ar0 * CC + u * 8;
    const unsigned short* Ap1 = A + (size_t)ar1 * CC + u * 8;
    const unsigned short* Bp0 = B + (size_t)bn0 * CC + u * 8;
    const unsigned short* Bp1 = B + (size_t)bn1 * CC + u * 8;

    f32x4 acc00 = (f32x4){0.f, 0.f, 0.f, 0.f};
    f32x4 acc01 = (f32x4){0.f, 0.f, 0.f, 0.f};
    f32x4 acc10 = (f32x4){0.f, 0.f, 0.f, 0.f};
    f32x4 acc11 = (f32x4){0.f, 0.f, 0.f, 0.f};
    #pragma unroll 4
    for (int k0 = 0; k0 < CC; k0 += 32) {
        const s16x8 a0 = *(const s16x8*)(Ap0 + k0);
        const s16x8 a1 = *(const s16x8*)(Ap1 + k0);
        const s16x8 b0 = *(const s16x8*)(Bp0 + k0);
        const s16x8 b1 = *(const s16x8*)(Bp1 + k0);
        acc00 = __builtin_amdgcn_mfma_f32_16x16x32_bf16(a0, b0, acc00, 0, 0, 0);
        acc01 = __builtin_amdgcn_mfma_f32_16x16x32_bf16(a0, b1, acc01, 0, 0, 0);
        acc10 = __builtin_amdgcn_mfma_f32_16x16x32_bf16(a1, b0, acc10, 0, 0, 0);
        acc11 = __builtin_amdgcn_mfma_f32_16x16x32_bf16(a1, b1, acc11, 0, 0, 0);
    }

    // epilogue: C/D layout col(fr)=n, row(u*4+r)=m (per 16x16 sub-tile)
    #pragma unroll
    for (int mi = 0; mi < 2; ++mi) {
        #pragma unroll
        for (int ni = 0; ni < 2; ++ni) {
            const f32x4 acc = mi ? (ni ? acc11 : acc10) : (ni ? acc01 : acc00);
            const int n = n0 + ni * 16 + fr;
            #pragma unroll
            for (int r = 0; r < 4; ++r) {
                const int m = m0 + mi * 16 + u * 4 + r;
                if (sel == 0) {
                    qT[((size_t)(n >> 6) * HW + m) * 64 + (n & 63)] = f2bf(acc[r] + bq[n]);
                } else if (sel == 1) {
                    kT[((size_t)(n >> 6) * PPK + m) * 64 + (n & 63)] = f2bf(acc[r] + bk[n]);
                } else {
                    vP[((size_t)(m >> 6) * 64 + (m & 63)) * PPK + n] = f2bf(acc[r] + bv[m]);
                }
            }
        }
    }
}

// ---------------------------------------------------------------------------
// Kernel 2: single-pass MFMA attention + epilogue, 8 waves. Block = (16q,
// head); grid (36, 8) = 288 blocks x 512 threads. QK: wave w owns p-slice
// [w*128, w*128+128); all 1024 p of bf16 weights live in LDS. Softmax
// max/sum reduce across waves via LDS + __syncthreads only (no cross-block
// traffic / fences — R1 post-mortem). PV: wave w owns (d-tile w&3,
// p-half w>>2); p-halves combined via small LDS reduce. Block writes
// out = gamma*O/l + x directly. 8 waves -> ~9 waves/CU during attn (vs 4.5
// for the 4-wave version) for load-latency hiding.
// ---------------------------------------------------------------------------
#define WLS 1040      // Wl row stride (shorts); bank step 8 -> verified pattern
__global__ __launch_bounds__(512) void attn5(
    const unsigned short* __restrict__ qT, const unsigned short* __restrict__ kT,
    const unsigned short* __restrict__ vP, const float* __restrict__ x,
    const float* __restrict__ gamma, float* __restrict__ out)
{
    const int q0 = blockIdx.x * 16;
    const int hd = blockIdx.y;
    const int t  = threadIdx.x;
    const int lane = t & 63, w = t >> 6;          // w in [0,8)
    const int fr = lane & 15, u = lane >> 4;

    __shared__ float cnt_s[PPK];                  // multiplicity table (0 for pads)
    __shared__ __align__(16) unsigned short Wl[16 * WLS];  // weights [q][1024p]
    __shared__ float mw[128], lw[128], sca[16];
    __shared__ float4 red[4][64];                 // PV p-half partials

    for (int i = t; i < PPK; i += 512) {          // cnt(y)*cnt(x), 0 for pads
        float c = 0.f;
        if (i < 900) {
            const int y = i / PW, xw = i - y * PW;
            int cy = y + 1;  if (PW - y  < cy) cy = PW - y;  if (cy > 7) cy = 7;
            int cx = xw + 1; if (PW - xw < cx) cx = PW - xw; if (cx > 7) cx = 7;
            c = (float)(cy * cx);
        }
        cnt_s[i] = c;
    }

    // q B-frags (shared across this wave's p-tiles)
    const unsigned short* qrow = qT + ((size_t)hd * HW + q0 + fr) * 64 + u * 8;
    const s16x8 b0 = *(const s16x8*)qrow;
    const s16x8 b1 = *(const s16x8*)(qrow + 32);

    // QK: 8 E^T tiles (16p x 16q) per wave -> this wave's 128 p
    f32x4 e[8];
    #pragma unroll
    for (int t4 = 0; t4 < 8; ++t4) {
        const unsigned short* krow =
            kT + ((size_t)hd * PPK + w * 128 + t4 * 16 + fr) * 64 + u * 8;
        const s16x8 a0 = *(const s16x8*)krow;
        const s16x8 a1 = *(const s16x8*)(krow + 32);
        f32x4 a = (f32x4){0.f, 0.f, 0.f, 0.f};
        a = __builtin_amdgcn_mfma_f32_16x16x32_bf16(a0, b0, a, 0, 0, 0);
        a = __builtin_amdgcn_mfma_f32_16x16x32_bf16(a1, b1, a, 0, 0, 0);
        e[t4] = a;
    }

    // per-q max over this wave's 128 p (regs share q = fr; cross-quad shuffles)
    float m = -1e30f;
    #pragma unroll
    for (int t4 = 0; t4 < 8; ++t4)
        #pragma unroll
        for (int r = 0; r < 4; ++r) m = fmaxf(m, e[t4][r]);
    m = fmaxf(m, __shfl_xor(m, 16));
    m = fmaxf(m, __shfl_xor(m, 32));
    if (lane < 16) mw[w * 16 + lane] = m;
    __syncthreads();                              // mw + cnt_s complete
    float mq = mw[fr];
    #pragma unroll
    for (int j = 1; j < 8; ++j) mq = fmaxf(mq, mw[j * 16 + fr]);

    // weights = cnt * exp(e - mq): bf16 into Wl; per-q partial sums
    float sum = 0.f;
    #pragma unroll
    for (int t4 = 0; t4 < 8; ++t4) {
        const float4 c4 = *(const float4*)&cnt_s[w * 128 + t4 * 16 + u * 4];
        const float cw[4] = {c4.x, c4.y, c4.z, c4.w};
        unsigned short wb4[4];
        #pragma unroll
        for (int r = 0; r < 4; ++r) {
            const float wv2 = cw[r] * __expf(e[t4][r] - mq);
            sum += wv2;
            wb4[r] = f2bf(wv2);
        }
        const int ho = fr * WLS + w * 128 + t4 * 16 + u * 4;
        *(unsigned*)&Wl[ho]     = (unsigned)wb4[0] | ((unsigned)wb4[1] << 16);
        *(unsigned*)&Wl[ho + 2] = (unsigned)wb4[2] | ((unsigned)wb4[3] << 16);
    }
    sum += __shfl_xor(sum, 16);
    sum += __shfl_xor(sum, 32);
    if (lane < 16) lw[w * 16 + lane] = sum;
    __syncthreads();                              // Wl + lw complete

    if (t < 16) {                                 // per-q scale = gamma / l
        float lq = 0.f;
        #pragma unroll
        for (int j = 0; j < 8; ++j) lq += lw[j * 16 + t];
        sca[t] = gamma[0] / lq;
    }

    // PV: wave w owns (d-tile w&3, p-half w>>2); O[16q][16d] over 512 p
    const int dt = w & 3, ph = w >> 2;
    f32x4 o = (f32x4){0.f, 0.f, 0.f, 0.f};
    const unsigned short* vrow =
        vP + ((size_t)hd * 64 + dt * 16 + fr) * PPK + ph * 512 + u * 8;
    #pragma unroll 8
    for (int c = 0; c < 16; ++c) {
        const s16x8 aw = *(const s16x8*)&Wl[fr * WLS + ph * 512 + c * 32 + u * 8];
        const s16x8 bv2 = *(const s16x8*)(vrow + c * 32);
        o = __builtin_amdgcn_mfma_f32_16x16x32_bf16(aw, bv2, o, 0, 0, 0);
    }
    if (w >= 4) red[dt][lane] = (float4){o[0], o[1], o[2], o[3]};
    __syncthreads();                              // red + sca ready
    if (w >= 4) return;

    // epilogue: C layout row=q (u*4+r), col=d (dt*16+fr); each lane stores a
    // float4 run of 4 consecutive q at row d -> 16B coalesced segments.
    const float4 r2 = red[dt][lane];
    const int d = hd * 64 + dt * 16 + fr;
    const size_t gb = (size_t)d * HW + q0 + u * 4;
    const float4 x4 = *(const float4*)&x[gb];
    float4 o4;
    o4.x = fmaf(sca[u * 4 + 0], o[0] + r2.x, x4.x);
    o4.y = fmaf(sca[u * 4 + 1], o[1] + r2.y, x4.y);
    o4.z = fmaf(sca[u * 4 + 2], o[2] + r2.z, x4.z);
    o4.w = fmaf(sca[u * 4 + 3], o[3] + r2.w, x4.w);
    *(float4*)&out[gb] = o4;
}

// ---------------------------------------------------------------------------
extern "C" void kernel_launch(void* const* d_in, const int* in_sizes, int n_in,
                              void* d_out, int out_size, void* d_ws, size_t ws_size,
                              hipStream_t stream) {
    const float* x     = (const float*)d_in[0];
    const float* Wq    = (const float*)d_in[1];
    const float* bq    = (const float*)d_in[2];
    const float* Wk    = (const float*)d_in[3];
    const float* bk    = (const float*)d_in[4];
    const float* Wv    = (const float*)d_in[5];
    const float* bv    = (const float*)d_in[6];
    const float* gamma = (const float*)d_in[7];
    float* out = (float*)d_out;

    char* wsb = (char*)d_ws;
    unsigned short* qT = (unsigned short*)(wsb + OFF_QT);
    unsigned short* kT = (unsigned short*)(wsb + OFF_KT);
    unsigned short* vP = (unsigned short*)(wsb + OFF_VP);
    unsigned short* xT = (unsigned short*)(wsb + OFF_XT);
    unsigned short* wb = (unsigned short*)(wsb + OFF_WB);

    cvtT<<<dim3(457), 256, 0, stream>>>(x, Wq, Wk, Wv, xT, wb);
    qkv_direct<<<dim3(328), 256, 0, stream>>>(xT, wb, bq, bk, bv, qT, kT, vP);
    attn5<<<dim3(36, 8), 512, 0, stream>>>(qT, kT, vP, x, gamma, out);
}

// Round 4
// 103.621 us; speedup vs baseline: 1.7454x; 1.0398x over previous
//
#include <hip/hip_runtime.h>

// Problem constants
#define HW   576      // 24*24 pixels
#define CC   512      // channels
#define PW   30       // padded H/W
#define PPK  1024     // padded p rows (900 real + pad)

typedef float f32x4 __attribute__((ext_vector_type(4)));
typedef short s16x8 __attribute__((ext_vector_type(8)));

__device__ __forceinline__ unsigned short f2bf(float f) {
    unsigned u = __float_as_uint(f);                      // RNE fp32->bf16
    return (unsigned short)((u + 0x7FFFu + ((u >> 16) & 1u)) >> 16);
}
__device__ __forceinline__ float bf2f(unsigned short h) {
    return __uint_as_float((unsigned)h << 16);
}
// reflect-pad row map; p>=900 -> zero row 576 of xT
__device__ __forceinline__ int smapf(int p) {
    if (p >= 900) return 576;
    const int y = p / PW, xw = p - y * PW;
    int iy = y - 3;  iy = (iy < 0) ? -iy : (iy > 23 ? 46 - iy : iy);
    int ix = xw - 3; ix = (ix < 0) ? -ix : (ix > 23 ? 46 - ix : ix);
    return iy * 24 + ix;
}

// Workspace byte offsets (total ~4.85 MB)
#define OFF_QT 0u         // bf16 [8][576][64]
#define OFF_KT 589824u    // bf16 [8][1024][64]
#define OFF_VP 1638400u   // bf16 [8][64][1024]
#define OFF_XT 2686976u   // bf16 [577][512] (row 576 = zeros)
#define OFF_WB 3277824u   // bf16 [3][512][512]

// ---------------------------------------------------------------------------
// Kernel 0: build xT (bf16 transpose of x, LDS-tiled 64x64, + zero row) and
// wb (bf16 copy of Wq/Wk/Wv). grid 457 blocks x 256.
// ---------------------------------------------------------------------------
__global__ __launch_bounds__(256) void cvtT(
    const float* __restrict__ x,
    const float* __restrict__ Wq, const float* __restrict__ Wk,
    const float* __restrict__ Wv,
    unsigned short* __restrict__ xT, unsigned short* __restrict__ wb)
{
    const int b = blockIdx.x, t = threadIdx.x;
    if (b < 72) {                                  // transpose: 9 pix-tiles x 8 chan-tiles
        __shared__ float tile[64][65];             // [chan][pix]; stride 65 -> 2-way free
        const int pt = b % 9, ct = b / 9;
        const int p0 = pt * 64, c0 = ct * 64;
        const int tr = t >> 4, tc4 = (t & 15) * 4;
        #pragma unroll
        for (int cr = 0; cr < 4; ++cr) {
            const int row = cr * 16 + tr;          // chan_local
            const float4 v = *(const float4*)&x[(size_t)(c0 + row) * HW + p0 + tc4];
            tile[row][tc4 + 0] = v.x;
            tile[row][tc4 + 1] = v.y;
            tile[row][tc4 + 2] = v.z;
            tile[row][tc4 + 3] = v.w;
        }
        __syncthreads();
        #pragma unroll
        for (int cr = 0; cr < 4; ++cr) {
            const int prow = cr * 16 + tr;         // pix_local
            ushort4 o;
            o.x = f2bf(tile[tc4 + 0][prow]);
            o.y = f2bf(tile[tc4 + 1][prow]);
            o.z = f2bf(tile[tc4 + 2][prow]);
            o.w = f2bf(tile[tc4 + 3][prow]);
            *(ushort4*)&xT[(size_t)(p0 + prow) * CC + c0 + tc4] = o;
        }
    } else if (b == 72) {                          // zero row 576
        if (t < 128) *(ushort4*)&xT[(size_t)576 * CC + t * 4] = (ushort4){0, 0, 0, 0};
    } else {                                       // W convert: 384 blocks x 2048 elems
        const int wi = (b - 73) * 2048 + t * 8;
        const int sel = wi >> 18, off = wi & 262143;
        const float* src = (sel == 0) ? Wq : (sel == 1) ? Wk : Wv;
        const float4 v0 = *(const float4*)&src[off];
        const float4 v1 = *(const float4*)&src[off + 4];
        ushort4 o0, o1;
        o0.x = f2bf(v0.x); o0.y = f2bf(v0.y); o0.z = f2bf(v0.z); o0.w = f2bf(v0.w);
        o1.x = f2bf(v1.x); o1.y = f2bf(v1.y); o1.z = f2bf(v1.z); o1.w = f2bf(v1.w);
        *(ushort4*)&wb[wi]     = o0;
        *(ushort4*)&wb[wi + 4] = o1;
    }
}

// ---------------------------------------------------------------------------
// Kernel 1: Q/K/V projections, K-split MFMA. One BLOCK = one 32x32 output
// tile; the block's 4 waves each cover K-range [w*128, w*128+128) (4 MFMA
// steps, 2 A-frags x 2 B-frags x 4 accs), then a one-barrier LDS f32x4
// reduce: wave w sums and stores 16x16 sub-tile w. 1312 blocks x 256 =
// 5248 waves (~5.1/SIMD, vs 1.28 for the R3 whole-K version) to hide the
// ~200-cycle L2 load latency. Same total L2 traffic (each operand byte read
// once per tile). Operands are contiguous 16B row-fragments straight from
// global (reflect-pad via smapf row indirection).
//   b <  288: D[pix][chan]  -> qT [head][pix][64]
//   b <  800: D[p][chan]    -> kT [head][p][64]   (pad rows: bias, harmless)
//   else    : D[chan][p]    -> vP [head][64][p]   (pad cols: bias, harmless)
// ---------------------------------------------------------------------------
__global__ __launch_bounds__(256) void qkv_ks(
    const unsigned short* __restrict__ xT, const unsigned short* __restrict__ wb,
    const float* __restrict__ bq, const float* __restrict__ bk,
    const float* __restrict__ bv,
    unsigned short* __restrict__ qT, unsigned short* __restrict__ kT,
    unsigned short* __restrict__ vP)
{
    const int b = blockIdx.x;
    const int t = threadIdx.x;
    const int lane = t & 63, w = t >> 6;
    const int fr = lane & 15, u = lane >> 4;

    int sel, m0, n0;
    if (b < 288)      { sel = 0; m0 = (b >> 4) << 5;               n0 = (b & 15) << 5; }
    else if (b < 800) { const int k = b - 288; sel = 1; m0 = (k >> 4) << 5; n0 = (k & 15) << 5; }
    else              { const int k = b - 800; sel = 2; m0 = (k >> 5) << 5; n0 = (k & 31) << 5; }

    const unsigned short *A, *B;
    int ar0, ar1, bn0, bn1;
    if (sel == 0)      { A = xT;          B = wb;
                         ar0 = m0 + fr;         ar1 = m0 + 16 + fr;
                         bn0 = n0 + fr;         bn1 = n0 + 16 + fr; }
    else if (sel == 1) { A = xT;          B = wb + 262144;
                         ar0 = smapf(m0 + fr);  ar1 = smapf(m0 + 16 + fr);
                         bn0 = n0 + fr;         bn1 = n0 + 16 + fr; }
    else               { A = wb + 524288; B = xT;
                         ar0 = m0 + fr;         ar1 = m0 + 16 + fr;
                         bn0 = smapf(n0 + fr);  bn1 = smapf(n0 + 16 + fr); }

    const int kw = w * 128;                       // this wave's K-range
    const unsigned short* Ap0 = A + (size_t)ar0 * CC + kw + u * 8;
    const unsigned short* Ap1 = A + (size_t)ar1 * CC + kw + u * 8;
    const unsigned short* Bp0 = B + (size_t)bn0 * CC + kw + u * 8;
    const unsigned short* Bp1 = B + (size_t)bn1 * CC + kw + u * 8;

    f32x4 acc00 = (f32x4){0.f, 0.f, 0.f, 0.f};
    f32x4 acc01 = (f32x4){0.f, 0.f, 0.f, 0.f};
    f32x4 acc10 = (f32x4){0.f, 0.f, 0.f, 0.f};
    f32x4 acc11 = (f32x4){0.f, 0.f, 0.f, 0.f};
    #pragma unroll
    for (int k0 = 0; k0 < 128; k0 += 32) {
        const s16x8 a0 = *(const s16x8*)(Ap0 + k0);
        const s16x8 a1 = *(const s16x8*)(Ap1 + k0);
        const s16x8 b0 = *(const s16x8*)(Bp0 + k0);
        const s16x8 b1 = *(const s16x8*)(Bp1 + k0);
        acc00 = __builtin_amdgcn_mfma_f32_16x16x32_bf16(a0, b0, acc00, 0, 0, 0);
        acc01 = __builtin_amdgcn_mfma_f32_16x16x32_bf16(a0, b1, acc01, 0, 0, 0);
        acc10 = __builtin_amdgcn_mfma_f32_16x16x32_bf16(a1, b0, acc10, 0, 0, 0);
        acc11 = __builtin_amdgcn_mfma_f32_16x16x32_bf16(a1, b1, acc11, 0, 0, 0);
    }

    // cross-wave K-reduce in LDS; wave w owns sub-tile (mi=w>>1, ni=w&1)
    __shared__ __align__(16) f32x4 red[4][4][64];  // [wave][subtile][lane]
    red[w][0][lane] = acc00;
    red[w][1][lane] = acc01;
    red[w][2][lane] = acc10;
    red[w][3][lane] = acc11;
    __syncthreads();

    f32x4 v = red[0][w][lane];
    #pragma unroll
    for (int w2 = 1; w2 < 4; ++w2) v = v + red[w2][w][lane];

    // epilogue: C/D layout col(fr)=n, row(u*4+r)=m (within 16x16 sub-tile)
    const int mi = w >> 1, ni = w & 1;
    const int n = n0 + ni * 16 + fr;
    #pragma unroll
    for (int r = 0; r < 4; ++r) {
        const int m = m0 + mi * 16 + u * 4 + r;
        if (sel == 0) {
            qT[((size_t)(n >> 6) * HW + m) * 64 + (n & 63)] = f2bf(v[r] + bq[n]);
        } else if (sel == 1) {
            kT[((size_t)(n >> 6) * PPK + m) * 64 + (n & 63)] = f2bf(v[r] + bk[n]);
        } else {
            vP[((size_t)(m >> 6) * 64 + (m & 63)) * PPK + n] = f2bf(v[r] + bv[m]);
        }
    }
}

// ---------------------------------------------------------------------------
// Kernel 2: single-pass MFMA attention + epilogue, 8 waves. Block = (16q,
// head); grid (36, 8) = 288 blocks x 512 threads. QK: wave w owns p-slice
// [w*128, w*128+128); all 1024 p of bf16 weights live in LDS. Softmax
// max/sum reduce across waves via LDS + __syncthreads only (no cross-block
// traffic / fences — R1 post-mortem). PV: wave w owns (d-tile w&3,
// p-half w>>2); p-halves combined via small LDS reduce. Block writes
// out = gamma*O/l + x directly.
// ---------------------------------------------------------------------------
#define WLS 1040      // Wl row stride (shorts); bank step 8 -> verified pattern
__global__ __launch_bounds__(512) void attn5(
    const unsigned short* __restrict__ qT, const unsigned short* __restrict__ kT,
    const unsigned short* __restrict__ vP, const float* __restrict__ x,
    const float* __restrict__ gamma, float* __restrict__ out)
{
    const int q0 = blockIdx.x * 16;
    const int hd = blockIdx.y;
    const int t  = threadIdx.x;
    const int lane = t & 63, w = t >> 6;          // w in [0,8)
    const int fr = lane & 15, u = lane >> 4;

    __shared__ float cnt_s[PPK];                  // multiplicity table (0 for pads)
    __shared__ __align__(16) unsigned short Wl[16 * WLS];  // weights [q][1024p]
    __shared__ float mw[128], lw[128], sca[16];
    __shared__ float4 red[4][64];                 // PV p-half partials

    for (int i = t; i < PPK; i += 512) {          // cnt(y)*cnt(x), 0 for pads
        float c = 0.f;
        if (i < 900) {
            const int y = i / PW, xw = i - y * PW;
            int cy = y + 1;  if (PW - y  < cy) cy = PW - y;  if (cy > 7) cy = 7;
            int cx = xw + 1; if (PW - xw < cx) cx = PW - xw; if (cx > 7) cx = 7;
            c = (float)(cy * cx);
        }
        cnt_s[i] = c;
    }

    // q B-frags (shared across this wave's p-tiles)
    const unsigned short* qrow = qT + ((size_t)hd * HW + q0 + fr) * 64 + u * 8;
    const s16x8 b0 = *(const s16x8*)qrow;
    const s16x8 b1 = *(const s16x8*)(qrow + 32);

    // QK: 8 E^T tiles (16p x 16q) per wave -> this wave's 128 p
    f32x4 e[8];
    #pragma unroll
    for (int t4 = 0; t4 < 8; ++t4) {
        const unsigned short* krow =
            kT + ((size_t)hd * PPK + w * 128 + t4 * 16 + fr) * 64 + u * 8;
        const s16x8 a0 = *(const s16x8*)krow;
        const s16x8 a1 = *(const s16x8*)(krow + 32);
        f32x4 a = (f32x4){0.f, 0.f, 0.f, 0.f};
        a = __builtin_amdgcn_mfma_f32_16x16x32_bf16(a0, b0, a, 0, 0, 0);
        a = __builtin_amdgcn_mfma_f32_16x16x32_bf16(a1, b1, a, 0, 0, 0);
        e[t4] = a;
    }

    // per-q max over this wave's 128 p (regs share q = fr; cross-quad shuffles)
    float m = -1e30f;
    #pragma unroll
    for (int t4 = 0; t4 < 8; ++t4)
        #pragma unroll
        for (int r = 0; r < 4; ++r) m = fmaxf(m, e[t4][r]);
    m = fmaxf(m, __shfl_xor(m, 16));
    m = fmaxf(m, __shfl_xor(m, 32));
    if (lane < 16) mw[w * 16 + lane] = m;
    __syncthreads();                              // mw + cnt_s complete
    float mq = mw[fr];
    #pragma unroll
    for (int j = 1; j < 8; ++j) mq = fmaxf(mq, mw[j * 16 + fr]);

    // weights = cnt * exp(e - mq): bf16 into Wl; per-q partial sums
    float sum = 0.f;
    #pragma unroll
    for (int t4 = 0; t4 < 8; ++t4) {
        const float4 c4 = *(const float4*)&cnt_s[w * 128 + t4 * 16 + u * 4];
        const float cw[4] = {c4.x, c4.y, c4.z, c4.w};
        unsigned short wb4[4];
        #pragma unroll
        for (int r = 0; r < 4; ++r) {
            const float wv2 = cw[r] * __expf(e[t4][r] - mq);
            sum += wv2;
            wb4[r] = f2bf(wv2);
        }
        const int ho = fr * WLS + w * 128 + t4 * 16 + u * 4;
        *(unsigned*)&Wl[ho]     = (unsigned)wb4[0] | ((unsigned)wb4[1] << 16);
        *(unsigned*)&Wl[ho + 2] = (unsigned)wb4[2] | ((unsigned)wb4[3] << 16);
    }
    sum += __shfl_xor(sum, 16);
    sum += __shfl_xor(sum, 32);
    if (lane < 16) lw[w * 16 + lane] = sum;
    __syncthreads();                              // Wl + lw complete

    if (t < 16) {                                 // per-q scale = gamma / l
        float lq = 0.f;
        #pragma unroll
        for (int j = 0; j < 8; ++j) lq += lw[j * 16 + t];
        sca[t] = gamma[0] / lq;
    }

    // PV: wave w owns (d-tile w&3, p-half w>>2); O[16q][16d] over 512 p
    const int dt = w & 3, ph = w >> 2;
    f32x4 o = (f32x4){0.f, 0.f, 0.f, 0.f};
    const unsigned short* vrow =
        vP + ((size_t)hd * 64 + dt * 16 + fr) * PPK + ph * 512 + u * 8;
    #pragma unroll 8
    for (int c = 0; c < 16; ++c) {
        const s16x8 aw = *(const s16x8*)&Wl[fr * WLS + ph * 512 + c * 32 + u * 8];
        const s16x8 bv2 = *(const s16x8*)(vrow + c * 32);
        o = __builtin_amdgcn_mfma_f32_16x16x32_bf16(aw, bv2, o, 0, 0, 0);
    }
    if (w >= 4) red[dt][lane] = (float4){o[0], o[1], o[2], o[3]};
    __syncthreads();                              // red + sca ready
    if (w >= 4) return;

    // epilogue: C layout row=q (u*4+r), col=d (dt*16+fr); each lane stores a
    // float4 run of 4 consecutive q at row d -> 16B coalesced segments.
    const float4 r2 = red[dt][lane];
    const int d = hd * 64 + dt * 16 + fr;
    const size_t gb = (size_t)d * HW + q0 + u * 4;
    const float4 x4 = *(const float4*)&x[gb];
    float4 o4;
    o4.x = fmaf(sca[u * 4 + 0], o[0] + r2.x, x4.x);
    o4.y = fmaf(sca[u * 4 + 1], o[1] + r2.y, x4.y);
    o4.z = fmaf(sca[u * 4 + 2], o[2] + r2.z, x4.z);
    o4.w = fmaf(sca[u * 4 + 3], o[3] + r2.w, x4.w);
    *(float4*)&out[gb] = o4;
}

// ---------------------------------------------------------------------------
extern "C" void kernel_launch(void* const* d_in, const int* in_sizes, int n_in,
                              void* d_out, int out_size, void* d_ws, size_t ws_size,
                              hipStream_t stream) {
    const float* x     = (const float*)d_in[0];
    const float* Wq    = (const float*)d_in[1];
    const float* bq    = (const float*)d_in[2];
    const float* Wk    = (const float*)d_in[3];
    const float* bk    = (const float*)d_in[4];
    const float* Wv    = (const float*)d_in[5];
    const float* bv    = (const float*)d_in[6];
    const float* gamma = (const float*)d_in[7];
    float* out = (float*)d_out;

    char* wsb = (char*)d_ws;
    unsigned short* qT = (unsigned short*)(wsb + OFF_QT);
    unsigned short* kT = (unsigned short*)(wsb + OFF_KT);
    unsigned short* vP = (unsigned short*)(wsb + OFF_VP);
    unsigned short* xT = (unsigned short*)(wsb + OFF_XT);
    unsigned short* wb = (unsigned short*)(wsb + OFF_WB);

    cvtT<<<dim3(457), 256, 0, stream>>>(x, Wq, Wk, Wv, xT, wb);
    qkv_ks<<<dim3(1312), 256, 0, stream>>>(xT, wb, bq, bk, bv, qT, kT, vP);
    attn5<<<dim3(36, 8), 512, 0, stream>>>(qT, kT, vP, x, gamma, out);
}